// Round 3
// baseline (454.517 us; speedup 1.0000x reference)
//
#include <hip/hip_runtime.h>
#include <hip/hip_bf16.h>
#include <math.h>

#define B 8
#define IC 256
#define OC 256
#define SDIM 512
#define H 128
#define W 128
#define OH 64
#define OW 64
#define EPS 1e-8f
#define SQRT2 1.41421356237309504880f
#define SCALE 0.02083333395421505f   // 1/sqrt(256*9)

#define RS 16640        // xbp row stride in elems (65*256)
#define PLANE 1081600   // 65*65*256 elems per phase plane

typedef unsigned short u16;
typedef unsigned int u32;
typedef __attribute__((ext_vector_type(8))) short s16x8;
typedef __attribute__((ext_vector_type(4))) float f32x4;

// ---------------- style = s @ style_w^T + style_b  [B, IC] ----------------
__global__ void style_kernel(const float* __restrict__ s,
                             const float* __restrict__ sw,
                             const float* __restrict__ sb,
                             float* __restrict__ style) {
    int i = blockIdx.x * 256 + threadIdx.x;
    int b = i >> 8, ic = i & 255;
    const float* sv = s + (size_t)b * SDIM;
    const float* wv = sw + (size_t)ic * SDIM;
    float sum = 0.f;
    for (int k = 0; k < SDIM; ++k) sum = fmaf(sv[k], wv[k], sum);
    style[i] = sum + sb[ic];
}

// ---------------- wsq[o,i] = sum_tap w^2 ----------------
__global__ void wsq_kernel(const float* __restrict__ w, float* __restrict__ wsq) {
    int i = blockIdx.x * 256 + threadIdx.x;
    const float* p = w + (size_t)i * 9;
    float sum = 0.f;
    for (int k = 0; k < 9; ++k) sum = fmaf(p[k], p[k], sum);
    wsq[i] = sum;
}

// ---------------- demod[b,o] = rsqrt(scale^2 * sum_i style^2*wsq + eps); zero ssq --------
__global__ void demod_kernel(const float* __restrict__ style,
                             const float* __restrict__ wsq,
                             float* __restrict__ demod,
                             float* __restrict__ ssq) {
    int i = blockIdx.x * 256 + threadIdx.x;   // b*256+o
    int b = i >> 8, o = i & 255;
    const float* st = style + b * 256;
    const float* wq = wsq + (size_t)o * 256;
    float sum = 0.f;
    for (int ic = 0; ic < 256; ++ic) {
        float sv = st[ic];
        sum = fmaf(sv * sv, wq[ic], sum);
    }
    demod[i] = rsqrtf(SCALE * SCALE * sum + EPS);
    ssq[i] = 0.f;
}

// ---------------- fused blur + pack ----------------
// Block: (strip of 8 output rows, 8-channel group, b). 256 threads = 2 rows x 128 cols.
// LDS: raw x [8ch][12 rows][128] fp32 (49KB) + bf16 vertical buffer [2][8][132].
// Writes channel-last phase planes directly + per-(b,c) ssq atomics.
__global__ __launch_bounds__(256, 3) void blurpack_kernel(const float* __restrict__ x,
                                                          __hip_bfloat16* __restrict__ xbp,
                                                          float* __restrict__ ssq) {
    __shared__ float img[8][12][128];
    __shared__ u16 vbuf[2][8][132];
    const int t = threadIdx.x;
    const int strip = blockIdx.x;     // 0..15
    const int ic0 = blockIdx.y << 3;  // channel group base
    const int b = blockIdx.z;

    // stage 12 rows x 8 ch (rows strip*8-2 .. strip*8+9, zero outside)
    #pragma unroll
    for (int k = 0; k < 12; ++k) {
        int e = t + (k << 8);                 // 0..3071 float4-slots
        int ch = e / 384;
        int rem = e - ch * 384;
        int r = rem >> 5, c4 = rem & 31;
        int gr = (strip << 3) - 2 + r;
        float4 v = {0.f, 0.f, 0.f, 0.f};
        if (gr >= 0 && gr < H)
            v = *(const float4*)(x + (((size_t)(b * 256 + ic0 + ch)) << 14) + (gr << 7) + (c4 << 2));
        *(float4*)&img[ch][r][c4 << 2] = v;
    }
    // zero vbuf halo columns (never written by vertical pass)
    if (t < 64) {
        int hr = t >> 5, ch = (t >> 2) & 7, sl = t & 3;
        vbuf[hr][ch][sl < 2 ? sl : 128 + sl] = 0;
    }

    const int hr = t >> 7;            // row within pair
    const int c = t & 127;            // full-res column
    const int wl = t & 63;
    float ss[8] = {0.f, 0.f, 0.f, 0.f, 0.f, 0.f, 0.f, 0.f};

    for (int pass = 0; pass < 4; ++pass) {
        int h_l = (pass << 1) + hr;   // output row within strip (0..7)
        __syncthreads();              // img ready (pass0) / prior reads done
        // vertical FIR (1 4 6 4 1) -> bf16 vbuf
        #pragma unroll
        for (int ch = 0; ch < 8; ++ch) {
            float a0 = img[ch][h_l][c],     a1 = img[ch][h_l + 1][c],
                  a2 = img[ch][h_l + 2][c], a3 = img[ch][h_l + 3][c],
                  a4 = img[ch][h_l + 4][c];
            float v = fmaf(6.f, a2, fmaf(4.f, a1 + a3, a0 + a4));
            __hip_bfloat16 bb = __float2bfloat16(v);
            vbuf[hr][ch][c + 2] = *(u16*)&bb;
        }
        __syncthreads();
        // horizontal FIR + pack 8 channels -> one 16B granule
        uint4 q;
        u16* qp = (u16*)&q;
        #pragma unroll
        for (int ch = 0; ch < 8; ++ch) {
            float s0 = __uint_as_float(((u32)vbuf[hr][ch][c]) << 16);
            float s1 = __uint_as_float(((u32)vbuf[hr][ch][c + 1]) << 16);
            float s2 = __uint_as_float(((u32)vbuf[hr][ch][c + 2]) << 16);
            float s3 = __uint_as_float(((u32)vbuf[hr][ch][c + 3]) << 16);
            float s4 = __uint_as_float(((u32)vbuf[hr][ch][c + 4]) << 16);
            float hs = fmaf(6.f, s2, fmaf(4.f, s1 + s3, s0 + s4)) * (1.0f / 256.0f);
            ss[ch] = fmaf(hs, hs, ss[ch]);
            __hip_bfloat16 ob = __float2bfloat16(hs);
            qp[ch] = *(u16*)&ob;
        }
        // phase decomposition: ph = hr (strip*8 even), pw = c&1
        size_t off = (size_t)((b << 2) + (hr << 1) + (c & 1)) * PLANE
                   + (size_t)((strip << 2) + pass + 1) * RS
                   + (size_t)((c >> 1) + 1) * 256 + ic0;
        *(uint4*)(xbp + off) = q;
    }

    // per-wave reduce ssq, one atomic per wave per channel
    #pragma unroll
    for (int ch = 0; ch < 8; ++ch) {
        float v = ss[ch];
        for (int o2 = 32; o2; o2 >>= 1) v += __shfl_down(v, o2, 64);
        if (wl == 0) atomicAdd(&ssq[(b << 8) + ic0 + ch], v);
    }
}

// ---------------- wf[b][o][t*256+ic] = w[o][ic][t] * demod[b,o] * factor(b,ic) (bf16) ----
__global__ void wf_kernel(const float* __restrict__ w,
                          const float* __restrict__ demod,
                          const float* __restrict__ ssq,
                          const float* __restrict__ style,
                          const float* __restrict__ g,
                          __hip_bfloat16* __restrict__ wf) {
    int bo = blockIdx.x;               // b*256+o
    int b = bo >> 8, o = bo & 255;
    int ic = threadIdx.x;
    float fac = rsqrtf(ssq[(b << 8) + ic] * (1.0f / 16384.0f) + EPS)
              * g[ic] * style[(b << 8) + ic] * SCALE;
    float m = demod[bo] * fac;
    const float* wp = w + ((size_t)o * 256 + ic) * 9;
    __hip_bfloat16* dst = wf + (size_t)bo * 2304 + ic;
    #pragma unroll
    for (int t = 0; t < 9; ++t)
        dst[t * 256] = __float2bfloat16(wp[t] * m);
}

// ---------------- zero the pad row 0 / col 0 of each phase plane ----------------
__global__ void zeropad_kernel(__hip_bfloat16* __restrict__ xbp) {
    int p = blockIdx.x;               // 0..31 (b*4+phase)
    int t = threadIdx.x;
    char* base = (char*)(xbp + (size_t)p * PLANE);
    uint4 z = {0u, 0u, 0u, 0u};
    for (int k = 0; k < 9; ++k) {
        int c = t + (k << 8);
        if (c < 2080) *(uint4*)(base + (size_t)c * 16) = z;
    }
    for (int k = 0; k < 8; ++k) {
        int c = t + (k << 8);
        int r = 1 + (c >> 5);
        int off = (c & 31) << 3;
        *(uint4*)(base + ((size_t)r * RS + off) * 2) = z;
    }
}

// ---------------- MFMA implicit-GEMM conv ----------------
__device__ __forceinline__ void gl_lds16(const void* g, void* l) {
    __builtin_amdgcn_global_load_lds((const __attribute__((address_space(1))) u32*)g,
                                     (__attribute__((address_space(3))) u32*)l, 16, 0, 0);
}

__global__ __launch_bounds__(256, 2) void conv_kernel(const __hip_bfloat16* __restrict__ xbp,
                                                      const __hip_bfloat16* __restrict__ wf,
                                                      const float* __restrict__ bias,
                                                      float* __restrict__ out) {
    __shared__ char lds[16384];       // A: [0,8192) 128 rows x 64B ; B: [8192,16384)
    const int t = threadIdx.x;
    const int o0 = blockIdx.x << 7;
    const int n0 = blockIdx.y << 7;
    const int b  = blockIdx.z;
    const size_t bb = (size_t)b << 8;

    const int mA  = t >> 2;
    const int kgl = t & 3;
    const int kga = kgl ^ ((mA >> 1) & 3);    // XOR swizzle
    size_t preA0 = (bb + o0 + mA) * 2304 + (kga << 3);
    size_t preA1 = preA0 + (size_t)64 * 2304;
    const int ow = mA & 63;
    size_t preB0 = (size_t)(blockIdx.y << 1) * RS + (size_t)ow * 256 + (kga << 3);
    size_t preB1 = preB0 + RS;
    char* dA0 = lds + t * 16;
    char* dA1 = lds + 4096 + t * 16;
    char* dB0 = lds + 8192 + t * 16;
    char* dB1 = lds + 12288 + t * 16;

    const int lane = t & 63, wave = t >> 6;
    const int lr = lane & 15, quad = lane >> 4;
    const int mb = (wave & 1) << 6;
    const int nb = (wave >> 1) << 6;
    const int fragoff = ((quad ^ ((lr >> 1) & 3)) << 4);

    f32x4 acc[4][4];
    #pragma unroll
    for (int i = 0; i < 4; ++i)
        #pragma unroll
        for (int j = 0; j < 4; ++j) acc[i][j] = (f32x4){0.f, 0.f, 0.f, 0.f};

    for (int kk = 0; kk < 72; ++kk) {
        int tap = kk >> 3;
        int ic0 = (kk & 7) << 5;
        int th = (tap * 11) >> 5;
        int tw = tap - th * 3;
        int ph  = (th == 1) ? 0 : 1;
        int dhp = (th == 0) ? 0 : 1;
        int pw  = (tw == 1) ? 0 : 1;
        int dwp = (tw == 0) ? 0 : 1;
        size_t boff = (size_t)((b << 2) + (ph << 1) + pw) * PLANE
                    + (size_t)dhp * RS + (dwp << 8) + ic0;
        size_t aoff = (size_t)kk << 5;

        __syncthreads();
        gl_lds16(wf + preA0 + aoff, dA0);
        gl_lds16(wf + preA1 + aoff, dA1);
        gl_lds16(xbp + preB0 + boff, dB0);
        gl_lds16(xbp + preB1 + boff, dB1);
        __syncthreads();

        s16x8 a[4], bf[4];
        #pragma unroll
        for (int i = 0; i < 4; ++i)
            a[i] = *(const s16x8*)(lds + ((mb + (i << 4) + lr) << 6) + fragoff);
        #pragma unroll
        for (int j = 0; j < 4; ++j)
            bf[j] = *(const s16x8*)(lds + 8192 + ((nb + (j << 4) + lr) << 6) + fragoff);
        #pragma unroll
        for (int i = 0; i < 4; ++i)
            #pragma unroll
            for (int j = 0; j < 4; ++j)
                acc[i][j] = __builtin_amdgcn_mfma_f32_16x16x32_bf16(a[i], bf[j], acc[i][j], 0, 0, 0);
    }

    float bi[4][4];
    #pragma unroll
    for (int i = 0; i < 4; ++i)
        #pragma unroll
        for (int rr = 0; rr < 4; ++rr)
            bi[i][rr] = bias[o0 + mb + (i << 4) + (quad << 2) + rr];
    #pragma unroll
    for (int i = 0; i < 4; ++i) {
        #pragma unroll
        for (int j = 0; j < 4; ++j) {
            #pragma unroll
            for (int rr = 0; rr < 4; ++rr) {
                int oc = o0 + mb + (i << 4) + (quad << 2) + rr;
                int n = n0 + nb + (j << 4) + lr;
                int oh = n >> 6, ow2 = n & 63;
                float v = acc[i][j][rr] + bi[i][rr];
                v = (v >= 0.f ? v : 0.2f * v) * SQRT2;
                out[((bb + oc) << 12) + (oh << 6) + ow2] = v;
            }
        }
    }
}

extern "C" void kernel_launch(void* const* d_in, const int* in_sizes, int n_in,
                              void* d_out, int out_size, void* d_ws, size_t ws_size,
                              hipStream_t stream) {
    const float* x   = (const float*)d_in[0];
    const float* s   = (const float*)d_in[1];
    const float* cw  = (const float*)d_in[2];
    const float* cb  = (const float*)d_in[3];
    const float* sw  = (const float*)d_in[4];
    const float* sb  = (const float*)d_in[5];
    const float* ng  = (const float*)d_in[6];
    float* out = (float*)d_out;

    char* ws = (char*)d_ws;
    __hip_bfloat16* xbp = (__hip_bfloat16*)ws;                   // 69,222,400 B
    __hip_bfloat16* wfb = (__hip_bfloat16*)(ws + 69222400);      //  9,437,184 B
    float* style  = (float*)(ws + 78659584);
    float* wsq    = style + 2048;
    float* demod  = wsq + 65536;
    float* ssq    = demod + 2048;

    style_kernel<<<8, 256, 0, stream>>>(s, sw, sb, style);
    wsq_kernel<<<256, 256, 0, stream>>>(cw, wsq);
    demod_kernel<<<8, 256, 0, stream>>>(style, wsq, demod, ssq);   // also zeroes ssq
    blurpack_kernel<<<dim3(16, 32, 8), 256, 0, stream>>>(x, xbp, ssq);
    wf_kernel<<<2048, 256, 0, stream>>>(cw, demod, ssq, style, ng, wfb);
    zeropad_kernel<<<32, 256, 0, stream>>>(xbp);
    conv_kernel<<<dim3(2, 32, 8), 256, 0, stream>>>(xbp, wfb, cb, out);
}

// Round 4
// 336.823 us; speedup vs baseline: 1.3494x; 1.3494x over previous
//
#include <hip/hip_runtime.h>
#include <hip/hip_bf16.h>
#include <math.h>

#define B 8
#define IC 256
#define OC 256
#define SDIM 512
#define H 128
#define W 128
#define OH 64
#define OW 64
#define EPS 1e-8f
#define SQRT2 1.41421356237309504880f
#define SCALE 0.02083333395421505f   // 1/sqrt(256*9)

#define RS 16640        // xbp row stride in elems (65*256)
#define PLANE 1081600   // 65*65*256 elems per phase plane

typedef unsigned short u16;
typedef unsigned int u32;
typedef __attribute__((ext_vector_type(8))) short s16x8;
typedef __attribute__((ext_vector_type(4))) float f32x4;

// ---------------- style = s @ style_w^T + style_b  [B, IC] ----------------
__global__ void style_kernel(const float* __restrict__ s,
                             const float* __restrict__ sw,
                             const float* __restrict__ sb,
                             float* __restrict__ style) {
    int i = blockIdx.x * 256 + threadIdx.x;
    int b = i >> 8, ic = i & 255;
    const float* sv = s + (size_t)b * SDIM;
    const float* wv = sw + (size_t)ic * SDIM;
    float sum = 0.f;
    for (int k = 0; k < SDIM; ++k) sum = fmaf(sv[k], wv[k], sum);
    style[i] = sum + sb[ic];
}

// ---------------- wsq[o,i] = sum_tap w^2 ----------------
__global__ void wsq_kernel(const float* __restrict__ w, float* __restrict__ wsq) {
    int i = blockIdx.x * 256 + threadIdx.x;
    const float* p = w + (size_t)i * 9;
    float sum = 0.f;
    for (int k = 0; k < 9; ++k) sum = fmaf(p[k], p[k], sum);
    wsq[i] = sum;
}

// ---------------- demod[b,o] = rsqrt(scale^2 * sum_i style^2*wsq + eps); zero ssq --------
__global__ void demod_kernel(const float* __restrict__ style,
                             const float* __restrict__ wsq,
                             float* __restrict__ demod,
                             float* __restrict__ ssq) {
    int i = blockIdx.x * 256 + threadIdx.x;   // b*256+o
    int b = i >> 8, o = i & 255;
    const float* st = style + b * 256;
    const float* wq = wsq + (size_t)o * 256;
    float sum = 0.f;
    for (int ic = 0; ic < 256; ++ic) {
        float sv = st[ic];
        sum = fmaf(sv * sv, wq[ic], sum);
    }
    demod[i] = rsqrtf(SCALE * SCALE * sum + EPS);
    ssq[i] = 0.f;
}

// ---------------- fused blur + pack v2 ----------------
// Block: (strip of 8 full-res rows, 8-channel group, b). 256 threads.
// raw x staged as bf16 [8ch][12r][128c] (24.6KB); v-FIR via ds_read_b128 into regs;
// h-FIR in regs with shuffle halos; pack-transpose via small double-buffered pbuf.
// 5 syncthreads/block, 4 blocks/CU.
__global__ __launch_bounds__(256, 4) void blurpack_kernel(const float* __restrict__ x,
                                                          __hip_bfloat16* __restrict__ xbp,
                                                          float* __restrict__ ssq) {
    __shared__ u16 raw[8][12][128];        // 24576 B
    __shared__ u16 pbuf[2][2][2][544];     // [dbuf][hr][pw][ch*64+pcol], pw stride 544hw
    const int t = threadIdx.x;
    const int strip = blockIdx.x;          // 0..15
    const int ic0 = blockIdx.y << 3;
    const int b = blockIdx.z;

    // ---- stage 12 rows x 8ch x 128 cols as bf16 (rows strip*8-2 .. strip*8+9) ----
    #pragma unroll
    for (int k = 0; k < 6; ++k) {
        int sidx = t + (k << 8);           // 0..1535 granules of 8 cols
        int ch = sidx / 192;
        int rem = sidx - ch * 192;
        int r = rem >> 4, cg = rem & 15;
        int gr = (strip << 3) - 2 + r;
        uint4 q = {0u, 0u, 0u, 0u};
        if (gr >= 0 && gr < H) {
            const float* p = x + (((size_t)(b * 256 + ic0 + ch)) << 14) + (gr << 7) + (cg << 3);
            float4 v0 = *(const float4*)p;
            float4 v1 = *(const float4*)(p + 4);
            u16* qp = (u16*)&q;
            const float* vv0 = &v0.x;
            const float* vv1 = &v1.x;
            #pragma unroll
            for (int j = 0; j < 4; ++j) {
                __hip_bfloat16 b0 = __float2bfloat16(vv0[j]);
                __hip_bfloat16 b1 = __float2bfloat16(vv1[j]);
                qp[j] = *(u16*)&b0;
                qp[4 + j] = *(u16*)&b1;
            }
        }
        *(uint4*)&raw[ch][r][cg << 3] = q;
    }
    __syncthreads();

    const int hr = t >> 7;                 // row within pair (0..1)
    const int ch = (t >> 4) & 7;
    const int cg = t & 15;                 // 8-col group
    float ssacc = 0.f;

    for (int pass = 0; pass < 4; ++pass) {
        const int dp = pass & 1;
        const int br = (pass << 1) + hr;   // out-row's buffer row (input rows br..br+4)

        // ---- vertical FIR (1 4 6 4 1) from LDS b128 reads ----
        float f0[8], f1[8], f2[8], f3[8], f4[8];
        {
            uint4 q0 = *(const uint4*)&raw[ch][br + 0][cg << 3];
            uint4 q1 = *(const uint4*)&raw[ch][br + 1][cg << 3];
            uint4 q2 = *(const uint4*)&raw[ch][br + 2][cg << 3];
            uint4 q3 = *(const uint4*)&raw[ch][br + 3][cg << 3];
            uint4 q4 = *(const uint4*)&raw[ch][br + 4][cg << 3];
            const u16* h0 = (const u16*)&q0; const u16* h1 = (const u16*)&q1;
            const u16* h2 = (const u16*)&q2; const u16* h3 = (const u16*)&q3;
            const u16* h4 = (const u16*)&q4;
            #pragma unroll
            for (int j = 0; j < 8; ++j) {
                f0[j] = __uint_as_float(((u32)h0[j]) << 16);
                f1[j] = __uint_as_float(((u32)h1[j]) << 16);
                f2[j] = __uint_as_float(((u32)h2[j]) << 16);
                f3[j] = __uint_as_float(((u32)h3[j]) << 16);
                f4[j] = __uint_as_float(((u32)h4[j]) << 16);
            }
        }
        float v[8];
        #pragma unroll
        for (int j = 0; j < 8; ++j)
            v[j] = fmaf(6.f, f2[j], fmaf(4.f, f1[j] + f3[j], f0[j] + f4[j]));

        // ---- horizontal FIR with shuffle halos ----
        float vm2 = __shfl_up(v[6], 1, 64);
        float vm1 = __shfl_up(v[7], 1, 64);
        float vp1 = __shfl_down(v[0], 1, 64);
        float vp2 = __shfl_down(v[1], 1, 64);
        if (cg == 0)  { vm2 = 0.f; vm1 = 0.f; }
        if (cg == 15) { vp1 = 0.f; vp2 = 0.f; }
        float e[12];
        e[0] = vm2; e[1] = vm1;
        #pragma unroll
        for (int j = 0; j < 8; ++j) e[2 + j] = v[j];
        e[10] = vp1; e[11] = vp2;

        u16 hp[8];
        #pragma unroll
        for (int j = 0; j < 8; ++j) {
            float hv = fmaf(6.f, e[j + 2], fmaf(4.f, e[j + 1] + e[j + 3], e[j] + e[j + 4]))
                     * (1.0f / 256.0f);
            ssacc = fmaf(hv, hv, ssacc);
            __hip_bfloat16 hb = __float2bfloat16(hv);
            hp[j] = *(u16*)&hb;
        }
        // pack-transpose: pw0 = even j, pw1 = odd j; pcol = cg*4 + j/2
        u16 w0[4] = {hp[0], hp[2], hp[4], hp[6]};
        u16 w1[4] = {hp[1], hp[3], hp[5], hp[7]};
        *(uint2*)&pbuf[dp][hr][0][(ch << 6) + (cg << 2)] = *(const uint2*)w0;
        *(uint2*)&pbuf[dp][hr][1][(ch << 6) + (cg << 2)] = *(const uint2*)w1;
        __syncthreads();

        // ---- granule assembly + store: thread t -> one 16B granule ----
        {
            int fc = t & 127;
            int hr2 = t >> 7;
            int pw = fc & 1, pcol = fc >> 1;
            uint4 g;
            u16* gp = (u16*)&g;
            #pragma unroll
            for (int c2 = 0; c2 < 8; ++c2)
                gp[c2] = pbuf[dp][hr2][pw][(c2 << 6) + pcol];
            size_t off = (size_t)((b << 2) + (hr2 << 1) + pw) * PLANE
                       + (size_t)((strip << 2) + pass + 1) * RS
                       + (size_t)(pcol + 1) * 256 + ic0;
            *(uint4*)(xbp + off) = g;
        }
    }

    // ---- ssq: reduce within 16-lane (same ch) groups, one atomic each ----
    float sv = ssacc;
    sv += __shfl_down(sv, 8, 16);
    sv += __shfl_down(sv, 4, 16);
    sv += __shfl_down(sv, 2, 16);
    sv += __shfl_down(sv, 1, 16);
    if (cg == 0) atomicAdd(&ssq[(b << 8) + ic0 + ch], sv);
}

// ---------------- wf[b][o][t*256+ic] = w[o][ic][t] * demod[b,o] * factor(b,ic) (bf16) ----
__global__ void wf_kernel(const float* __restrict__ w,
                          const float* __restrict__ demod,
                          const float* __restrict__ ssq,
                          const float* __restrict__ style,
                          const float* __restrict__ g,
                          __hip_bfloat16* __restrict__ wf) {
    int bo = blockIdx.x;               // b*256+o
    int b = bo >> 8, o = bo & 255;
    int ic = threadIdx.x;
    float fac = rsqrtf(ssq[(b << 8) + ic] * (1.0f / 16384.0f) + EPS)
              * g[ic] * style[(b << 8) + ic] * SCALE;
    float m = demod[bo] * fac;
    const float* wp = w + ((size_t)o * 256 + ic) * 9;
    __hip_bfloat16* dst = wf + (size_t)bo * 2304 + ic;
    #pragma unroll
    for (int t = 0; t < 9; ++t)
        dst[t * 256] = __float2bfloat16(wp[t] * m);
}

// ---------------- zero the pad row 0 / col 0 of each phase plane ----------------
__global__ void zeropad_kernel(__hip_bfloat16* __restrict__ xbp) {
    int p = blockIdx.x;               // 0..31 (b*4+phase)
    int t = threadIdx.x;
    char* base = (char*)(xbp + (size_t)p * PLANE);
    uint4 z = {0u, 0u, 0u, 0u};
    for (int k = 0; k < 9; ++k) {
        int c = t + (k << 8);
        if (c < 2080) *(uint4*)(base + (size_t)c * 16) = z;
    }
    for (int k = 0; k < 8; ++k) {
        int c = t + (k << 8);
        int r = 1 + (c >> 5);
        int off = (c & 31) << 3;
        *(uint4*)(base + ((size_t)r * RS + off) * 2) = z;
    }
}

// ---------------- MFMA implicit-GEMM conv ----------------
__device__ __forceinline__ void gl_lds16(const void* g, void* l) {
    __builtin_amdgcn_global_load_lds((const __attribute__((address_space(1))) u32*)g,
                                     (__attribute__((address_space(3))) u32*)l, 16, 0, 0);
}

__global__ __launch_bounds__(256, 2) void conv_kernel(const __hip_bfloat16* __restrict__ xbp,
                                                      const __hip_bfloat16* __restrict__ wf,
                                                      const float* __restrict__ bias,
                                                      float* __restrict__ out) {
    __shared__ char lds[16384];       // A: [0,8192) 128 rows x 64B ; B: [8192,16384)
    const int t = threadIdx.x;
    const int o0 = blockIdx.x << 7;
    const int n0 = blockIdx.y << 7;
    const int b  = blockIdx.z;
    const size_t bb = (size_t)b << 8;

    const int mA  = t >> 2;
    const int kgl = t & 3;
    const int kga = kgl ^ ((mA >> 1) & 3);    // XOR swizzle
    size_t preA0 = (bb + o0 + mA) * 2304 + (kga << 3);
    size_t preA1 = preA0 + (size_t)64 * 2304;
    const int ow = mA & 63;
    size_t preB0 = (size_t)(blockIdx.y << 1) * RS + (size_t)ow * 256 + (kga << 3);
    size_t preB1 = preB0 + RS;
    char* dA0 = lds + t * 16;
    char* dA1 = lds + 4096 + t * 16;
    char* dB0 = lds + 8192 + t * 16;
    char* dB1 = lds + 12288 + t * 16;

    const int lane = t & 63, wave = t >> 6;
    const int lr = lane & 15, quad = lane >> 4;
    const int mb = (wave & 1) << 6;
    const int nb = (wave >> 1) << 6;
    const int fragoff = ((quad ^ ((lr >> 1) & 3)) << 4);

    f32x4 acc[4][4];
    #pragma unroll
    for (int i = 0; i < 4; ++i)
        #pragma unroll
        for (int j = 0; j < 4; ++j) acc[i][j] = (f32x4){0.f, 0.f, 0.f, 0.f};

    for (int kk = 0; kk < 72; ++kk) {
        int tap = kk >> 3;
        int ic0 = (kk & 7) << 5;
        int th = (tap * 11) >> 5;
        int tw = tap - th * 3;
        int ph  = (th == 1) ? 0 : 1;
        int dhp = (th == 0) ? 0 : 1;
        int pw  = (tw == 1) ? 0 : 1;
        int dwp = (tw == 0) ? 0 : 1;
        size_t boff = (size_t)((b << 2) + (ph << 1) + pw) * PLANE
                    + (size_t)dhp * RS + (dwp << 8) + ic0;
        size_t aoff = (size_t)kk << 5;

        __syncthreads();
        gl_lds16(wf + preA0 + aoff, dA0);
        gl_lds16(wf + preA1 + aoff, dA1);
        gl_lds16(xbp + preB0 + boff, dB0);
        gl_lds16(xbp + preB1 + boff, dB1);
        __syncthreads();

        s16x8 a[4], bf[4];
        #pragma unroll
        for (int i = 0; i < 4; ++i)
            a[i] = *(const s16x8*)(lds + ((mb + (i << 4) + lr) << 6) + fragoff);
        #pragma unroll
        for (int j = 0; j < 4; ++j)
            bf[j] = *(const s16x8*)(lds + 8192 + ((nb + (j << 4) + lr) << 6) + fragoff);
        #pragma unroll
        for (int i = 0; i < 4; ++i)
            #pragma unroll
            for (int j = 0; j < 4; ++j)
                acc[i][j] = __builtin_amdgcn_mfma_f32_16x16x32_bf16(a[i], bf[j], acc[i][j], 0, 0, 0);
    }

    float bi[4][4];
    #pragma unroll
    for (int i = 0; i < 4; ++i)
        #pragma unroll
        for (int rr = 0; rr < 4; ++rr)
            bi[i][rr] = bias[o0 + mb + (i << 4) + (quad << 2) + rr];
    #pragma unroll
    for (int i = 0; i < 4; ++i) {
        #pragma unroll
        for (int j = 0; j < 4; ++j) {
            #pragma unroll
            for (int rr = 0; rr < 4; ++rr) {
                int oc = o0 + mb + (i << 4) + (quad << 2) + rr;
                int n = n0 + nb + (j << 4) + lr;
                int oh = n >> 6, ow2 = n & 63;
                float v = acc[i][j][rr] + bi[i][rr];
                v = (v >= 0.f ? v : 0.2f * v) * SQRT2;
                out[((bb + oc) << 12) + (oh << 6) + ow2] = v;
            }
        }
    }
}

extern "C" void kernel_launch(void* const* d_in, const int* in_sizes, int n_in,
                              void* d_out, int out_size, void* d_ws, size_t ws_size,
                              hipStream_t stream) {
    const float* x   = (const float*)d_in[0];
    const float* s   = (const float*)d_in[1];
    const float* cw  = (const float*)d_in[2];
    const float* cb  = (const float*)d_in[3];
    const float* sw  = (const float*)d_in[4];
    const float* sb  = (const float*)d_in[5];
    const float* ng  = (const float*)d_in[6];
    float* out = (float*)d_out;

    char* ws = (char*)d_ws;
    __hip_bfloat16* xbp = (__hip_bfloat16*)ws;                   // 69,222,400 B
    __hip_bfloat16* wfb = (__hip_bfloat16*)(ws + 69222400);      //  9,437,184 B
    float* style  = (float*)(ws + 78659584);
    float* wsq    = style + 2048;
    float* demod  = wsq + 65536;
    float* ssq    = demod + 2048;

    style_kernel<<<8, 256, 0, stream>>>(s, sw, sb, style);
    wsq_kernel<<<256, 256, 0, stream>>>(cw, wsq);
    demod_kernel<<<8, 256, 0, stream>>>(style, wsq, demod, ssq);   // also zeroes ssq
    blurpack_kernel<<<dim3(16, 32, 8), 256, 0, stream>>>(x, xbp, ssq);
    wf_kernel<<<2048, 256, 0, stream>>>(cw, demod, ssq, style, ng, wfb);
    zeropad_kernel<<<32, 256, 0, stream>>>(xbp);
    conv_kernel<<<dim3(2, 32, 8), 256, 0, stream>>>(xbp, wfb, cb, out);
}

// Round 5
// 322.757 us; speedup vs baseline: 1.4082x; 1.0436x over previous
//
#include <hip/hip_runtime.h>
#include <hip/hip_bf16.h>
#include <math.h>

#define B 8
#define IC 256
#define OC 256
#define SDIM 512
#define H 128
#define W 128
#define OH 64
#define OW 64
#define EPS 1e-8f
#define SQRT2 1.41421356237309504880f
#define SCALE 0.02083333395421505f   // 1/sqrt(256*9)

#define RS 16640        // xbp row stride in elems (65*256)
#define PLANE 1081600   // 65*65*256 elems per phase plane

typedef unsigned short u16;
typedef unsigned int u32;
typedef __attribute__((ext_vector_type(8))) short s16x8;
typedef __attribute__((ext_vector_type(4))) float f32x4;

// ---------------- wsq[o,i] = sum_tap w^2 ----------------
__global__ void wsq_kernel(const float* __restrict__ w, float* __restrict__ wsq) {
    int i = blockIdx.x * 256 + threadIdx.x;
    const float* p = w + (size_t)i * 9;
    float sum = 0.f;
    for (int k = 0; k < 9; ++k) sum = fmaf(p[k], p[k], sum);
    wsq[i] = sum;
}

// ---------------- fused style + demod (one block per batch b); also zeroes ssq ------------
__global__ __launch_bounds__(256) void style_demod_kernel(const float* __restrict__ s,
                                                          const float* __restrict__ sw,
                                                          const float* __restrict__ sb,
                                                          const float* __restrict__ wsq,
                                                          float* __restrict__ style,
                                                          float* __restrict__ demod,
                                                          float* __restrict__ ssq) {
    __shared__ float st[256];
    const int b = blockIdx.x;
    const int tid = threadIdx.x;
    // style[b, tid]
    const float4* sv = (const float4*)(s + (size_t)b * SDIM);
    const float4* wv = (const float4*)(sw + (size_t)tid * SDIM);
    float sum = 0.f;
    #pragma unroll 4
    for (int k = 0; k < 128; ++k) {
        float4 a4 = sv[k], b4 = wv[k];
        sum = fmaf(a4.x, b4.x, fmaf(a4.y, b4.y, fmaf(a4.z, b4.z, fmaf(a4.w, b4.w, sum))));
    }
    float styv = sum + sb[tid];
    style[(b << 8) + tid] = styv;
    st[tid] = styv;
    ssq[(b << 8) + tid] = 0.f;
    __syncthreads();
    // demod[b, o=tid]
    const float4* wq = (const float4*)(wsq + (size_t)tid * 256);
    float acc = 0.f;
    #pragma unroll 4
    for (int k = 0; k < 64; ++k) {
        float4 q = wq[k];
        float s0 = st[4 * k], s1 = st[4 * k + 1], s2 = st[4 * k + 2], s3 = st[4 * k + 3];
        acc = fmaf(s0 * s0, q.x, fmaf(s1 * s1, q.y, fmaf(s2 * s2, q.z, fmaf(s3 * s3, q.w, acc))));
    }
    demod[(b << 8) + tid] = rsqrtf(SCALE * SCALE * acc + EPS);
}

// ---------------- fused blur + pack v3: 4-row strips, 6 blocks/CU ----------------
__global__ __launch_bounds__(256, 6) void blurpack_kernel(const float* __restrict__ x,
                                                          __hip_bfloat16* __restrict__ xbp,
                                                          float* __restrict__ ssq) {
    __shared__ u16 raw[8][8][128];         // 16384 B
    __shared__ u16 pbuf[2][2][2][544];     // 8704 B
    const int t = threadIdx.x;
    const int strip = blockIdx.x;          // 0..31 (4 full-res rows each)
    const int ic0 = blockIdx.y << 3;
    const int b = blockIdx.z;

    // stage 8 rows (strip*4-2 .. strip*4+5) x 8 ch x 128 cols as bf16
    #pragma unroll
    for (int k = 0; k < 4; ++k) {
        int sidx = t + (k << 8);           // 0..1023 granules of 8 cols
        int ch = sidx >> 7;
        int rem = sidx & 127;
        int r = rem >> 4, cg = rem & 15;
        int gr = (strip << 2) - 2 + r;
        uint4 q = {0u, 0u, 0u, 0u};
        if (gr >= 0 && gr < H) {
            const float* p = x + (((size_t)(b * 256 + ic0 + ch)) << 14) + (gr << 7) + (cg << 3);
            float4 v0 = *(const float4*)p;
            float4 v1 = *(const float4*)(p + 4);
            u16* qp = (u16*)&q;
            const float* vv0 = &v0.x;
            const float* vv1 = &v1.x;
            #pragma unroll
            for (int j = 0; j < 4; ++j) {
                __hip_bfloat16 b0 = __float2bfloat16(vv0[j]);
                __hip_bfloat16 b1 = __float2bfloat16(vv1[j]);
                qp[j] = *(u16*)&b0;
                qp[4 + j] = *(u16*)&b1;
            }
        }
        *(uint4*)&raw[ch][r][cg << 3] = q;
    }
    __syncthreads();

    const int hr = t >> 7;                 // row within pair (0..1)
    const int ch = (t >> 4) & 7;
    const int cg = t & 15;
    float ssacc = 0.f;

    #pragma unroll
    for (int pass = 0; pass < 2; ++pass) {
        const int br = (pass << 1) + hr;   // reads raw rows br..br+4

        float v[8];
        {
            uint4 q0 = *(const uint4*)&raw[ch][br + 0][cg << 3];
            uint4 q1 = *(const uint4*)&raw[ch][br + 1][cg << 3];
            uint4 q2 = *(const uint4*)&raw[ch][br + 2][cg << 3];
            uint4 q3 = *(const uint4*)&raw[ch][br + 3][cg << 3];
            uint4 q4 = *(const uint4*)&raw[ch][br + 4][cg << 3];
            const u16* h0 = (const u16*)&q0; const u16* h1 = (const u16*)&q1;
            const u16* h2 = (const u16*)&q2; const u16* h3 = (const u16*)&q3;
            const u16* h4 = (const u16*)&q4;
            #pragma unroll
            for (int j = 0; j < 8; ++j) {
                float f0 = __uint_as_float(((u32)h0[j]) << 16);
                float f1 = __uint_as_float(((u32)h1[j]) << 16);
                float f2 = __uint_as_float(((u32)h2[j]) << 16);
                float f3 = __uint_as_float(((u32)h3[j]) << 16);
                float f4 = __uint_as_float(((u32)h4[j]) << 16);
                v[j] = fmaf(6.f, f2, fmaf(4.f, f1 + f3, f0 + f4));
            }
        }

        float vm2 = __shfl_up(v[6], 1, 64);
        float vm1 = __shfl_up(v[7], 1, 64);
        float vp1 = __shfl_down(v[0], 1, 64);
        float vp2 = __shfl_down(v[1], 1, 64);
        if (cg == 0)  { vm2 = 0.f; vm1 = 0.f; }
        if (cg == 15) { vp1 = 0.f; vp2 = 0.f; }
        float e[12];
        e[0] = vm2; e[1] = vm1;
        #pragma unroll
        for (int j = 0; j < 8; ++j) e[2 + j] = v[j];
        e[10] = vp1; e[11] = vp2;

        u16 hp[8];
        #pragma unroll
        for (int j = 0; j < 8; ++j) {
            float hv = fmaf(6.f, e[j + 2], fmaf(4.f, e[j + 1] + e[j + 3], e[j] + e[j + 4]))
                     * (1.0f / 256.0f);
            ssacc = fmaf(hv, hv, ssacc);
            __hip_bfloat16 hb = __float2bfloat16(hv);
            hp[j] = *(u16*)&hb;
        }
        u16 w0[4] = {hp[0], hp[2], hp[4], hp[6]};
        u16 w1[4] = {hp[1], hp[3], hp[5], hp[7]};
        *(uint2*)&pbuf[pass][hr][0][(ch << 6) + (cg << 2)] = *(const uint2*)w0;
        *(uint2*)&pbuf[pass][hr][1][(ch << 6) + (cg << 2)] = *(const uint2*)w1;
        __syncthreads();

        {
            int fc = t & 127;
            int hr2 = t >> 7;
            int pw = fc & 1, pcol = fc >> 1;
            uint4 g;
            u16* gp = (u16*)&g;
            #pragma unroll
            for (int c2 = 0; c2 < 8; ++c2)
                gp[c2] = pbuf[pass][hr2][pw][(c2 << 6) + pcol];
            size_t off = (size_t)((b << 2) + (hr2 << 1) + pw) * PLANE
                       + (size_t)((strip << 1) + pass + 1) * RS
                       + (size_t)(pcol + 1) * 256 + ic0;
            *(uint4*)(xbp + off) = g;
        }
    }

    float sv2 = ssacc;
    sv2 += __shfl_down(sv2, 8, 16);
    sv2 += __shfl_down(sv2, 4, 16);
    sv2 += __shfl_down(sv2, 2, 16);
    sv2 += __shfl_down(sv2, 1, 16);
    if (cg == 0) atomicAdd(&ssq[(b << 8) + ic0 + ch], sv2);
}

// ---------------- wf + zeropad fused ----------------
__global__ void wf_kernel(const float* __restrict__ w,
                          const float* __restrict__ demod,
                          const float* __restrict__ ssq,
                          const float* __restrict__ style,
                          const float* __restrict__ g,
                          __hip_bfloat16* __restrict__ wf,
                          __hip_bfloat16* __restrict__ xbp) {
    int bo = blockIdx.x;               // b*256+o
    int b = bo >> 8, o = bo & 255;
    int ic = threadIdx.x;
    float fac = rsqrtf(ssq[(b << 8) + ic] * (1.0f / 16384.0f) + EPS)
              * g[ic] * style[(b << 8) + ic] * SCALE;
    float m = demod[bo] * fac;
    const float* wp = w + ((size_t)o * 256 + ic) * 9;
    __hip_bfloat16* dst = wf + (size_t)bo * 2304 + ic;
    #pragma unroll
    for (int t = 0; t < 9; ++t)
        dst[t * 256] = __float2bfloat16(wp[t] * m);

    // zeropad: blocks 0..31 each clear pad row0/col0 of one phase plane
    if (bo < 32) {
        int t = threadIdx.x;
        char* base = (char*)(xbp + (size_t)bo * PLANE);
        uint4 z = {0u, 0u, 0u, 0u};
        for (int k = 0; k < 9; ++k) {
            int c = t + (k << 8);
            if (c < 2080) *(uint4*)(base + (size_t)c * 16) = z;
        }
        for (int k = 0; k < 8; ++k) {
            int c = t + (k << 8);
            int r = 1 + (c >> 5);
            int off = (c & 31) << 3;
            *(uint4*)(base + ((size_t)r * RS + off) * 2) = z;
        }
    }
}

// ---------------- MFMA implicit-GEMM conv, BK=128 (18 iters) ----------------
__device__ __forceinline__ void gl_lds16(const void* g, void* l) {
    __builtin_amdgcn_global_load_lds((const __attribute__((address_space(1))) u32*)g,
                                     (__attribute__((address_space(3))) u32*)l, 16, 0, 0);
}

__global__ __launch_bounds__(256, 2) void conv_kernel(const __hip_bfloat16* __restrict__ xbp,
                                                      const __hip_bfloat16* __restrict__ wf,
                                                      const float* __restrict__ bias,
                                                      float* __restrict__ out) {
    __shared__ char lds[65536];       // A: [0,32768) 128 rows x 256B ; B: [32768,65536)
    const int t = threadIdx.x;
    const int o0 = blockIdx.x << 7;
    const int y  = blockIdx.y;        // n-tile (128 n = 2 oh rows)
    const int b  = blockIdx.z;
    const size_t bb = (size_t)b << 8;

    // staging byte-offsets for 8 A slots + 8 B slots (slot s = t + 256*j)
    // slot (row r, pos m) holds global granule g = m ^ (r&7)  [bank spread for readers]
    u32 aoffs[8], boffs[8];
    #pragma unroll
    for (int j = 0; j < 8; ++j) {
        int s = t + (j << 8);
        int r = s >> 4, m = s & 15;
        int g = m ^ (r & 7);
        aoffs[j] = (u32)(r * 2304 + (g << 3)) * 2;
        boffs[j] = (u32)((((y << 1) + (r >> 6)) * RS) + ((r & 63) << 8) + (g << 3)) * 2;
    }
    char* ldsA = lds;
    char* ldsB = lds + 32768;
    char* dstA = ldsA + t * 16;
    char* dstB = ldsB + t * 16;
    const char* gAbase = (const char*)(wf + (bb + o0) * 2304);

    const int lane = t & 63, wave = t >> 6;
    const int lr = lane & 15, quad = lane >> 4;
    const int mb = (wave & 1) << 6;
    const int nb = (wave >> 1) << 6;

    f32x4 acc[4][4];
    #pragma unroll
    for (int i = 0; i < 4; ++i)
        #pragma unroll
        for (int j = 0; j < 4; ++j) acc[i][j] = (f32x4){0.f, 0.f, 0.f, 0.f};

    for (int c = 0; c < 18; ++c) {
        int tap = c >> 1;
        int ich = (c & 1) << 7;
        int th = (tap * 11) >> 5;
        int tw = tap - th * 3;
        int ph  = (th == 1) ? 0 : 1;
        int dhp = (th == 0) ? 0 : 1;
        int pw  = (tw == 1) ? 0 : 1;
        int dwp = (tw == 0) ? 0 : 1;
        const char* gA = gAbase + (size_t)(tap * 256 + ich) * 2;
        const char* gB = (const char*)(xbp + (size_t)((b << 2) + (ph << 1) + pw) * PLANE
                                       + (size_t)dhp * RS + (dwp << 8) + ich);
        __syncthreads();
        #pragma unroll
        for (int j = 0; j < 8; ++j) gl_lds16(gA + aoffs[j], dstA + (j << 12));
        #pragma unroll
        for (int j = 0; j < 8; ++j) gl_lds16(gB + boffs[j], dstB + (j << 12));
        __syncthreads();

        #pragma unroll
        for (int s = 0; s < 4; ++s) {
            const int mq = ((s << 2) + quad) ^ (lr & 7);
            s16x8 a[4], bf[4];
            #pragma unroll
            for (int i = 0; i < 4; ++i)
                a[i] = *(const s16x8*)(ldsA + ((mb + (i << 4) + lr) << 8) + (mq << 4));
            #pragma unroll
            for (int j = 0; j < 4; ++j)
                bf[j] = *(const s16x8*)(ldsB + ((nb + (j << 4) + lr) << 8) + (mq << 4));
            #pragma unroll
            for (int i = 0; i < 4; ++i)
                #pragma unroll
                for (int j = 0; j < 4; ++j)
                    acc[i][j] = __builtin_amdgcn_mfma_f32_16x16x32_bf16(a[i], bf[j], acc[i][j], 0, 0, 0);
        }
    }

    // epilogue: bias + scaled LeakyReLU
    float bi[4][4];
    #pragma unroll
    for (int i = 0; i < 4; ++i)
        #pragma unroll
        for (int rr = 0; rr < 4; ++rr)
            bi[i][rr] = bias[o0 + mb + (i << 4) + (quad << 2) + rr];
    const int n0 = y << 7;
    #pragma unroll
    for (int i = 0; i < 4; ++i) {
        #pragma unroll
        for (int j = 0; j < 4; ++j) {
            #pragma unroll
            for (int rr = 0; rr < 4; ++rr) {
                int oc = o0 + mb + (i << 4) + (quad << 2) + rr;
                int n = n0 + nb + (j << 4) + lr;
                int oh = n >> 6, ow2 = n & 63;
                float v = acc[i][j][rr] + bi[i][rr];
                v = (v >= 0.f ? v : 0.2f * v) * SQRT2;
                out[((bb + oc) << 12) + (oh << 6) + ow2] = v;
            }
        }
    }
}

extern "C" void kernel_launch(void* const* d_in, const int* in_sizes, int n_in,
                              void* d_out, int out_size, void* d_ws, size_t ws_size,
                              hipStream_t stream) {
    const float* x   = (const float*)d_in[0];
    const float* s   = (const float*)d_in[1];
    const float* cw  = (const float*)d_in[2];
    const float* cb  = (const float*)d_in[3];
    const float* sw  = (const float*)d_in[4];
    const float* sb  = (const float*)d_in[5];
    const float* ng  = (const float*)d_in[6];
    float* out = (float*)d_out;

    char* ws = (char*)d_ws;
    __hip_bfloat16* xbp = (__hip_bfloat16*)ws;                   // 69,222,400 B
    __hip_bfloat16* wfb = (__hip_bfloat16*)(ws + 69222400);      //  9,437,184 B
    float* style  = (float*)(ws + 78659584);
    float* wsq    = style + 2048;
    float* demod  = wsq + 65536;
    float* ssq    = demod + 2048;

    wsq_kernel<<<256, 256, 0, stream>>>(cw, wsq);
    style_demod_kernel<<<8, 256, 0, stream>>>(s, sw, sb, wsq, style, demod, ssq);
    blurpack_kernel<<<dim3(32, 32, 8), 256, 0, stream>>>(x, xbp, ssq);
    wf_kernel<<<2048, 256, 0, stream>>>(cw, demod, ssq, style, ng, wfb, xbp);
    conv_kernel<<<dim3(2, 32, 8), 256, 0, stream>>>(xbp, wfb, cb, out);
}